// Round 1
// baseline (249.356 us; speedup 1.0000x reference)
//
#include <hip/hip_runtime.h>
#include <hip/hip_bf16.h>
#include <cstdint>

// RoPE MHA fused pipeline, round 0.
// B=2, L=2048, D=1024, H=16, HD=64.  All GEMMs bf16 MFMA 16x16x32, fp32 accum.

constexpr int NB = 2, NL = 2048, ND = 1024, NH = 16, NHD = 64;
constexpr int NM = NB * NL; // 4096 tokens

typedef __bf16 bf16_t;
typedef __bf16 bf16x8 __attribute__((ext_vector_type(8)));
typedef __bf16 bf16x4 __attribute__((ext_vector_type(4)));
typedef float f32x4 __attribute__((ext_vector_type(4)));

typedef const __attribute__((address_space(1))) void* gas_ptr;
typedef __attribute__((address_space(3))) void* las_ptr;

__device__ __forceinline__ void async_load16(const void* g, void* l) {
  __builtin_amdgcn_global_load_lds((gas_ptr)g, (las_ptr)l, 16, 0, 0);
}

// ---------------------------------------------------------------- conversion
__global__ __launch_bounds__(256) void cvt_kernel(const float* __restrict__ src,
                                                  bf16_t* __restrict__ dst, int n4) {
  int i = blockIdx.x * blockDim.x + threadIdx.x;
  if (i >= n4) return;
  float4 v = ((const float4*)src)[i];
  bf16x4 o;
  o[0] = (bf16_t)v.x; o[1] = (bf16_t)v.y; o[2] = (bf16_t)v.z; o[3] = (bf16_t)v.w;
  ((bf16x4*)dst)[i] = o;
}

// ---------------------------------------------------------------- GEMM
// C[m][n] = sum_k A[m][k] * W[n][k]  (+bias) ; A: NM x ND bf16, W: 1024 x 1024 bf16 (row = out feat)
// MODE 1: fused QKVG projection, N=4096 (ntile>>3 selects tensor). Epilogue: rope(Q,K)->bf16,
//         V->bf16 transposed (B,H,HD,L), G raw fp32.
// MODE 0: out projection, N=1024, epilogue: +bias -> fp32 Out.
template <int MODE>
__global__ __launch_bounds__(256) void gemm_kernel(
    const bf16_t* __restrict__ Aq, const bf16_t* __restrict__ Ak, const bf16_t* __restrict__ Av,
    const bf16_t* __restrict__ W0, const bf16_t* __restrict__ W1,
    const bf16_t* __restrict__ W2, const bf16_t* __restrict__ W3,
    const float* __restrict__ b0, const float* __restrict__ b1,
    const float* __restrict__ b2, const float* __restrict__ b3,
    const float* __restrict__ ctab, const float* __restrict__ stab,
    bf16_t* __restrict__ Qr, bf16_t* __restrict__ Kr, bf16_t* __restrict__ Vt,
    float* __restrict__ Gp, float* __restrict__ Out) {
  __shared__ bf16_t lA[128 * 64];
  __shared__ bf16_t lB[128 * 64];
  const int ntile = blockIdx.x, mtile = blockIdx.y;
  const int tid = threadIdx.x, lane = tid & 63, w = tid >> 6;
  const int wm = w >> 1, wn = w & 1;
  const int lr = lane & 15, lg = lane >> 4;

  const bf16_t* Asrc;
  const bf16_t* Wsrc;
  int nofs, t = 0;
  if constexpr (MODE == 1) {
    t = ntile >> 3;
    Asrc = (t == 1) ? Ak : (t == 2) ? Av : Aq;
    Wsrc = (t == 0) ? W0 : (t == 1) ? W1 : (t == 2) ? W2 : W3;
    nofs = (ntile & 7) * 128;
  } else {
    Asrc = Aq; Wsrc = W0; nofs = ntile * 128;
  }
  const bf16_t* Ablk = Asrc + mtile * 128 * ND;
  const bf16_t* Wblk = Wsrc + nofs * ND;

  f32x4 acc[4][4];
#pragma unroll
  for (int i = 0; i < 4; ++i)
#pragma unroll
    for (int j = 0; j < 4; ++j)
#pragma unroll
      for (int k = 0; k < 4; ++k) acc[i][j][k] = 0.f;

  for (int kb = 0; kb < 16; ++kb) {
    // stage A,B tiles (128x64 bf16 each) with XOR swizzle on the global source
#pragma unroll
    for (int p = 0; p < 4; ++p) {
      int q = w * 256 + p * 64 + lane;
      int r = q >> 3, c = q & 7;
      int cs = c ^ (r & 7);
      async_load16(Ablk + r * ND + kb * 64 + cs * 8, lA + (w * 256 + p * 64) * 8);
      async_load16(Wblk + r * ND + kb * 64 + cs * 8, lB + (w * 256 + p * 64) * 8);
    }
    __syncthreads();
#pragma unroll
    for (int ks = 0; ks < 2; ++ks) {
      bf16x8 af[4], bfr[4];
#pragma unroll
      for (int i = 0; i < 4; ++i) {
        int ra = wm * 64 + i * 16 + lr;
        int ca = (ks * 4 + lg) ^ (ra & 7);
        af[i] = *(const bf16x8*)(lA + ra * 64 + ca * 8);
        int rb = wn * 64 + i * 16 + lr;
        int cb = (ks * 4 + lg) ^ (rb & 7);
        bfr[i] = *(const bf16x8*)(lB + rb * 64 + cb * 8);
      }
#pragma unroll
      for (int i = 0; i < 4; ++i)
#pragma unroll
        for (int j = 0; j < 4; ++j)
          acc[i][j] = __builtin_amdgcn_mfma_f32_16x16x32_bf16(af[i], bfr[j], acc[i][j], 0, 0, 0);
    }
    __syncthreads();
  }

  // epilogue: C/D layout col = lane&15, row = (lane>>4)*4 + reg
  if constexpr (MODE == 0) {
#pragma unroll
    for (int j = 0; j < 4; ++j) {
      int nn = ntile * 128 + wn * 64 + j * 16 + lr;
      float bias = b0[nn];
#pragma unroll
      for (int i = 0; i < 4; ++i)
#pragma unroll
        for (int rg = 0; rg < 4; ++rg) {
          int mm = mtile * 128 + wm * 64 + i * 16 + lg * 4 + rg;
          Out[mm * ND + nn] = acc[i][j][rg] + bias;
        }
    }
  } else {
    const int fbase = nofs + wn * 64;   // 64-aligned -> single head per wave-col
    const int h = fbase >> 6;
    if (t < 2) {
      bf16_t* dst = (t == 0) ? Qr : Kr;
      const float* bias = (t == 0) ? b0 : b1;
#pragma unroll
      for (int i = 0; i < 4; ++i)
#pragma unroll
        for (int rg = 0; rg < 4; ++rg) {
          int mm = mtile * 128 + wm * 64 + i * 16 + lg * 4 + rg;
          int bb = mm >> 11, l = mm & (NL - 1);
          bf16_t* rowp = dst + ((bb * NH + h) * NL + l) * NHD;
          const float* crow = ctab + l * NHD;
          const float* srow = stab + l * NHD;
#pragma unroll
          for (int j = 0; j < 2; ++j) {   // rope pairs: (d, d+32) = frag cols (j, j+2)
            int dlo = j * 16 + lr, dhi = dlo + 32;
            float xlo = acc[i][j][rg] + bias[fbase + dlo];
            float xhi = acc[i][j + 2][rg] + bias[fbase + dhi];
            float olo = xlo * crow[dlo] - xhi * srow[dlo];
            float ohi = xhi * crow[dhi] + xlo * srow[dhi];
            rowp[dlo] = (bf16_t)olo;
            rowp[dhi] = (bf16_t)ohi;
          }
        }
    } else if (t == 2) {
#pragma unroll
      for (int i = 0; i < 4; ++i)
#pragma unroll
        for (int rg = 0; rg < 4; ++rg) {
          int mm = mtile * 128 + wm * 64 + i * 16 + lg * 4 + rg;
          int bb = mm >> 11, l = mm & (NL - 1);
#pragma unroll
          for (int j = 0; j < 4; ++j) {
            int d = j * 16 + lr;
            float x = acc[i][j][rg] + b2[fbase + d];
            Vt[((bb * NH + h) * NHD + d) * NL + l] = (bf16_t)x;  // transposed layout
          }
        }
    } else {
#pragma unroll
      for (int i = 0; i < 4; ++i)
#pragma unroll
        for (int rg = 0; rg < 4; ++rg) {
          int mm = mtile * 128 + wm * 64 + i * 16 + lg * 4 + rg;
#pragma unroll
          for (int j = 0; j < 4; ++j) {
            int f = fbase + j * 16 + lr;
            Gp[mm * ND + f] = acc[i][j][rg] + b3[f];  // raw pre-sigmoid
          }
        }
    }
  }
}

// ---------------------------------------------------------------- flash attention
// grid (L/64, B*H); block 256 = 4 waves, wave w owns 16 q-rows.
__global__ __launch_bounds__(256) void attn_kernel(
    const bf16_t* __restrict__ Qr, const bf16_t* __restrict__ Kr, const bf16_t* __restrict__ Vt,
    const int* __restrict__ mask, const float* __restrict__ Gp, bf16_t* __restrict__ X) {
  __shared__ bf16_t lK[64 * 64];
  __shared__ bf16_t lV[64 * 64];
  __shared__ float lM[64];
  __shared__ bf16_t lP[4][16 * 80];   // per-wave P transpose buffer, padded stride 80
  const int qb = blockIdx.x, bh = blockIdx.y;
  const int bb = bh >> 4, h = bh & 15;
  const int tid = threadIdx.x, lane = tid & 63, w = tid >> 6;
  const int lr = lane & 15, lg = lane >> 4;
  const float scale = 0.125f;  // 1/sqrt(64)

  // Q fragments held in registers for the whole kernel
  const bf16_t* Qbase = Qr + (bh * NL + qb * 64 + w * 16 + lr) * NHD;
  bf16x8 aq0 = *(const bf16x8*)(Qbase + lg * 8);
  bf16x8 aq1 = *(const bf16x8*)(Qbase + 32 + lg * 8);

  f32x4 acc[4];
#pragma unroll
  for (int j = 0; j < 4; ++j)
#pragma unroll
    for (int k = 0; k < 4; ++k) acc[j][k] = 0.f;
  float mrun[4], lrun[4];
#pragma unroll
  for (int r = 0; r < 4; ++r) { mrun[r] = -1e30f; lrun[r] = 0.f; }

  const bf16_t* Kbh = Kr + bh * NL * NHD;
  const bf16_t* Vbh = Vt + bh * NHD * NL;

  for (int kb = 0; kb < NL / 64; ++kb) {
    // ---- stage K (64x64, contiguous) and V^T (64 d-rows x 64 kk) with XOR swizzle
#pragma unroll
    for (int p = 0; p < 2; ++p) {
      int q = w * 128 + p * 64 + lane;
      int r = q >> 3, c = q & 7;
      int cs = c ^ (r & 7);
      async_load16(Kbh + (kb * 64 + r) * NHD + cs * 8, lK + (w * 128 + p * 64) * 8);
      async_load16(Vbh + r * NL + kb * 64 + cs * 8, lV + (w * 128 + p * 64) * 8);
    }
    if (tid < 64)
      lM[tid] = mask[bb * NL + kb * 64 + tid] ? -__builtin_inff() : 0.f;
    __syncthreads();

    // ---- S = Q K^T   (16q x 64k per wave)
    f32x4 sc[4];
#pragma unroll
    for (int j = 0; j < 4; ++j) {
#pragma unroll
      for (int k = 0; k < 4; ++k) sc[j][k] = 0.f;
      int r = j * 16 + lr;
      int c0 = (lg) ^ (r & 7);
      int c1 = (4 + lg) ^ (r & 7);
      bf16x8 bk0 = *(const bf16x8*)(lK + r * 64 + c0 * 8);
      bf16x8 bk1 = *(const bf16x8*)(lK + r * 64 + c1 * 8);
      sc[j] = __builtin_amdgcn_mfma_f32_16x16x32_bf16(aq0, bk0, sc[j], 0, 0, 0);
      sc[j] = __builtin_amdgcn_mfma_f32_16x16x32_bf16(aq1, bk1, sc[j], 0, 0, 0);
    }

    // ---- online softmax (rows live on lanes sharing lg; cols across lr x 4 frags)
    float p[4][4], cfac[4];
#pragma unroll
    for (int rg = 0; rg < 4; ++rg) {
      float sv[4];
      float mx = -__builtin_inff();
#pragma unroll
      for (int j = 0; j < 4; ++j) {
        float s = sc[j][rg] * scale + lM[j * 16 + lr];
        sv[j] = s;
        mx = fmaxf(mx, s);
      }
#pragma unroll
      for (int off = 1; off < 16; off <<= 1) mx = fmaxf(mx, __shfl_xor(mx, off, 64));
      float mnew = fmaxf(mrun[rg], mx);
      float c = __expf(mrun[rg] - mnew);
      float rsum = 0.f;
#pragma unroll
      for (int j = 0; j < 4; ++j) {
        float pv = __expf(sv[j] - mnew);
        p[j][rg] = pv;
        rsum += pv;
      }
#pragma unroll
      for (int off = 1; off < 16; off <<= 1) rsum += __shfl_xor(rsum, off, 64);
      lrun[rg] = lrun[rg] * c + rsum;
      mrun[rg] = mnew;
      cfac[rg] = c;
    }
#pragma unroll
    for (int j = 0; j < 4; ++j)
#pragma unroll
      for (int rg = 0; rg < 4; ++rg) acc[j][rg] *= cfac[rg];

    // ---- transpose P through LDS into A-fragment layout
    bf16_t* Pw = lP[w];
#pragma unroll
    for (int j = 0; j < 4; ++j)
#pragma unroll
      for (int rg = 0; rg < 4; ++rg)
        Pw[(lg * 4 + rg) * 80 + j * 16 + lr] = (bf16_t)p[j][rg];
    __syncthreads();
    bf16x8 pa0 = *(const bf16x8*)(Pw + lr * 80 + lg * 8);
    bf16x8 pa1 = *(const bf16x8*)(Pw + lr * 80 + 32 + lg * 8);

    // ---- acc += P V
#pragma unroll
    for (int j = 0; j < 4; ++j) {
      int r = j * 16 + lr;
      int c0 = (lg) ^ (r & 7);
      int c1 = (4 + lg) ^ (r & 7);
      bf16x8 bv0 = *(const bf16x8*)(lV + r * 64 + c0 * 8);
      bf16x8 bv1 = *(const bf16x8*)(lV + r * 64 + c1 * 8);
      acc[j] = __builtin_amdgcn_mfma_f32_16x16x32_bf16(pa0, bv0, acc[j], 0, 0, 0);
      acc[j] = __builtin_amdgcn_mfma_f32_16x16x32_bf16(pa1, bv1, acc[j], 0, 0, 0);
    }
    __syncthreads();
  }

  // ---- epilogue: /l, * sigmoid(gate), -> bf16 X (B,L,D)
#pragma unroll
  for (int rg = 0; rg < 4; ++rg) {
    float rinv = lrun[rg] > 0.f ? 1.f / lrun[rg] : 0.f;
    int q = qb * 64 + w * 16 + lg * 4 + rg;
    int rowbase = (bb * NL + q) * ND + h * NHD;
#pragma unroll
    for (int j = 0; j < 4; ++j) {
      int d = j * 16 + lr;
      float g = Gp[rowbase + d];
      float gate = 1.f / (1.f + __expf(-g));
      X[rowbase + d] = (bf16_t)(acc[j][rg] * rinv * gate);
    }
  }
}

// ---------------------------------------------------------------- launch
extern "C" void kernel_launch(void* const* d_in, const int* in_sizes, int n_in,
                              void* d_out, int out_size, void* d_ws, size_t ws_size,
                              hipStream_t stream) {
  const float* query = (const float*)d_in[0];
  const float* key   = (const float*)d_in[1];
  const float* value = (const float*)d_in[2];
  const int*   maskp = (const int*)d_in[3];
  const float* rcos  = (const float*)d_in[4];
  const float* rsin  = (const float*)d_in[5];
  const float* Wq = (const float*)d_in[6];  const float* bq = (const float*)d_in[7];
  const float* Wk = (const float*)d_in[8];  const float* bk = (const float*)d_in[9];
  const float* Wv = (const float*)d_in[10]; const float* bv = (const float*)d_in[11];
  const float* Wg = (const float*)d_in[12]; const float* bg = (const float*)d_in[13];
  const float* Wo = (const float*)d_in[14]; const float* bo = (const float*)d_in[15];

  constexpr size_t MB = 1ull << 20;
  char* ws = (char*)d_ws;
  bf16_t* qbb = (bf16_t*)(ws + 0 * MB);    // 8 MB  query bf16
  bf16_t* kbb = (bf16_t*)(ws + 8 * MB);    // 8 MB  key bf16
  bf16_t* vbb = (bf16_t*)(ws + 16 * MB);   // 8 MB  value bf16
  bf16_t* wqb = (bf16_t*)(ws + 24 * MB);   // 2 MB each
  bf16_t* wkb = (bf16_t*)(ws + 26 * MB);
  bf16_t* wvb = (bf16_t*)(ws + 28 * MB);
  bf16_t* wgb = (bf16_t*)(ws + 30 * MB);
  bf16_t* wob = (bf16_t*)(ws + 32 * MB);
  bf16_t* Qr  = (bf16_t*)(ws + 34 * MB);   // 8 MB (B,H,L,HD) roped
  bf16_t* Kr  = (bf16_t*)(ws + 42 * MB);   // 8 MB
  bf16_t* Vt  = (bf16_t*)(ws + 50 * MB);   // 8 MB (B,H,HD,L)
  float*  Gp  = (float*)(ws + 58 * MB);    // 16 MB raw gate fp32
  bf16_t* Xb  = (bf16_t*)(ws + 74 * MB);   // 8 MB attn-out * gate

  // fp32 -> bf16 conversions
  cvt_kernel<<<4096, 256, 0, stream>>>(query, qbb, (NM * ND) / 4);
  cvt_kernel<<<4096, 256, 0, stream>>>(key,   kbb, (NM * ND) / 4);
  cvt_kernel<<<4096, 256, 0, stream>>>(value, vbb, (NM * ND) / 4);
  cvt_kernel<<<1024, 256, 0, stream>>>(Wq, wqb, (ND * ND) / 4);
  cvt_kernel<<<1024, 256, 0, stream>>>(Wk, wkb, (ND * ND) / 4);
  cvt_kernel<<<1024, 256, 0, stream>>>(Wv, wvb, (ND * ND) / 4);
  cvt_kernel<<<1024, 256, 0, stream>>>(Wg, wgb, (ND * ND) / 4);
  cvt_kernel<<<1024, 256, 0, stream>>>(Wo, wob, (ND * ND) / 4);

  // fused QKVG projection + rope + layouts
  gemm_kernel<1><<<dim3(32, 32), 256, 0, stream>>>(
      qbb, kbb, vbb, wqb, wkb, wvb, wgb, bq, bk, bv, bg, rcos, rsin,
      Qr, Kr, Vt, Gp, nullptr);

  // flash attention + gate
  attn_kernel<<<dim3(32, 32), 256, 0, stream>>>(Qr, Kr, Vt, maskp, Gp, Xb);

  // output projection
  gemm_kernel<0><<<dim3(8, 32), 256, 0, stream>>>(
      Xb, nullptr, nullptr, wob, nullptr, nullptr, nullptr,
      bo, nullptr, nullptr, nullptr, nullptr, nullptr,
      nullptr, nullptr, nullptr, nullptr, (float*)d_out);
}

// Round 2
// 227.196 us; speedup vs baseline: 1.0975x; 1.0975x over previous
//
#include <hip/hip_runtime.h>
#include <hip/hip_bf16.h>
#include <cstdint>

// RoPE MHA fused pipeline, round 1: swapped-QK^T 32x32 flash attention.
// B=2, L=2048, D=1024, H=16, HD=64.

constexpr int NB = 2, NL = 2048, ND = 1024, NH = 16, NHD = 64;
constexpr int NM = NB * NL; // 4096 tokens

typedef __bf16 bf16_t;
typedef __bf16 bf16x8 __attribute__((ext_vector_type(8)));
typedef __bf16 bf16x4 __attribute__((ext_vector_type(4)));
typedef float f32x4 __attribute__((ext_vector_type(4)));
typedef float f32x16 __attribute__((ext_vector_type(16)));
typedef unsigned int uint2v __attribute__((ext_vector_type(2)));

typedef const __attribute__((address_space(1))) void* gas_ptr;
typedef __attribute__((address_space(3))) void* las_ptr;

__device__ __forceinline__ void async_load16(const void* g, void* l) {
  __builtin_amdgcn_global_load_lds((gas_ptr)g, (las_ptr)l, 16, 0, 0);
}

__device__ __forceinline__ unsigned cvtpk_bf16(float lo, float hi) {
  unsigned r;
  asm("v_cvt_pk_bf16_f32 %0, %1, %2" : "=v"(r) : "v"(lo), "v"(hi));
  return r;
}

__device__ __forceinline__ void pl32_swap(unsigned& a, unsigned& b) {
#if __has_builtin(__builtin_amdgcn_permlane32_swap)
  uint2v r = __builtin_amdgcn_permlane32_swap(a, b, false, false);
  a = r.x; b = r.y;
#else
  asm volatile("v_permlane32_swap_b32 %0, %1" : "+v"(a), "+v"(b));
#endif
}

// ---------------------------------------------------------------- conversion
__global__ __launch_bounds__(256) void cvt_kernel(const float* __restrict__ src,
                                                  bf16_t* __restrict__ dst, int n4) {
  int i = blockIdx.x * blockDim.x + threadIdx.x;
  if (i >= n4) return;
  float4 v = ((const float4*)src)[i];
  bf16x4 o;
  o[0] = (bf16_t)v.x; o[1] = (bf16_t)v.y; o[2] = (bf16_t)v.z; o[3] = (bf16_t)v.w;
  ((bf16x4*)dst)[i] = o;
}

// ---------------------------------------------------------------- GEMM (unchanged from r0)
template <int MODE>
__global__ __launch_bounds__(256) void gemm_kernel(
    const bf16_t* __restrict__ Aq, const bf16_t* __restrict__ Ak, const bf16_t* __restrict__ Av,
    const bf16_t* __restrict__ W0, const bf16_t* __restrict__ W1,
    const bf16_t* __restrict__ W2, const bf16_t* __restrict__ W3,
    const float* __restrict__ b0, const float* __restrict__ b1,
    const float* __restrict__ b2, const float* __restrict__ b3,
    const float* __restrict__ ctab, const float* __restrict__ stab,
    bf16_t* __restrict__ Qr, bf16_t* __restrict__ Kr, bf16_t* __restrict__ Vt,
    float* __restrict__ Gp, float* __restrict__ Out) {
  __shared__ bf16_t lA[128 * 64];
  __shared__ bf16_t lB[128 * 64];
  const int ntile = blockIdx.x, mtile = blockIdx.y;
  const int tid = threadIdx.x, lane = tid & 63, w = tid >> 6;
  const int wm = w >> 1, wn = w & 1;
  const int lr = lane & 15, lg = lane >> 4;

  const bf16_t* Asrc;
  const bf16_t* Wsrc;
  int nofs, t = 0;
  if constexpr (MODE == 1) {
    t = ntile >> 3;
    Asrc = (t == 1) ? Ak : (t == 2) ? Av : Aq;
    Wsrc = (t == 0) ? W0 : (t == 1) ? W1 : (t == 2) ? W2 : W3;
    nofs = (ntile & 7) * 128;
  } else {
    Asrc = Aq; Wsrc = W0; nofs = ntile * 128;
  }
  const bf16_t* Ablk = Asrc + mtile * 128 * ND;
  const bf16_t* Wblk = Wsrc + nofs * ND;

  f32x4 acc[4][4];
#pragma unroll
  for (int i = 0; i < 4; ++i)
#pragma unroll
    for (int j = 0; j < 4; ++j)
#pragma unroll
      for (int k = 0; k < 4; ++k) acc[i][j][k] = 0.f;

  for (int kb = 0; kb < 16; ++kb) {
#pragma unroll
    for (int p = 0; p < 4; ++p) {
      int q = w * 256 + p * 64 + lane;
      int r = q >> 3, c = q & 7;
      int cs = c ^ (r & 7);
      async_load16(Ablk + r * ND + kb * 64 + cs * 8, lA + (w * 256 + p * 64) * 8);
      async_load16(Wblk + r * ND + kb * 64 + cs * 8, lB + (w * 256 + p * 64) * 8);
    }
    __syncthreads();
#pragma unroll
    for (int ks = 0; ks < 2; ++ks) {
      bf16x8 af[4], bfr[4];
#pragma unroll
      for (int i = 0; i < 4; ++i) {
        int ra = wm * 64 + i * 16 + lr;
        int ca = (ks * 4 + lg) ^ (ra & 7);
        af[i] = *(const bf16x8*)(lA + ra * 64 + ca * 8);
        int rb = wn * 64 + i * 16 + lr;
        int cb = (ks * 4 + lg) ^ (rb & 7);
        bfr[i] = *(const bf16x8*)(lB + rb * 64 + cb * 8);
      }
#pragma unroll
      for (int i = 0; i < 4; ++i)
#pragma unroll
        for (int j = 0; j < 4; ++j)
          acc[i][j] = __builtin_amdgcn_mfma_f32_16x16x32_bf16(af[i], bfr[j], acc[i][j], 0, 0, 0);
    }
    __syncthreads();
  }

  if constexpr (MODE == 0) {
#pragma unroll
    for (int j = 0; j < 4; ++j) {
      int nn = ntile * 128 + wn * 64 + j * 16 + lr;
      float bias = b0[nn];
#pragma unroll
      for (int i = 0; i < 4; ++i)
#pragma unroll
        for (int rg = 0; rg < 4; ++rg) {
          int mm = mtile * 128 + wm * 64 + i * 16 + lg * 4 + rg;
          Out[mm * ND + nn] = acc[i][j][rg] + bias;
        }
    }
  } else {
    const int fbase = nofs + wn * 64;
    const int h = fbase >> 6;
    if (t < 2) {
      bf16_t* dst = (t == 0) ? Qr : Kr;
      const float* bias = (t == 0) ? b0 : b1;
#pragma unroll
      for (int i = 0; i < 4; ++i)
#pragma unroll
        for (int rg = 0; rg < 4; ++rg) {
          int mm = mtile * 128 + wm * 64 + i * 16 + lg * 4 + rg;
          int bb = mm >> 11, l = mm & (NL - 1);
          bf16_t* rowp = dst + ((bb * NH + h) * NL + l) * NHD;
          const float* crow = ctab + l * NHD;
          const float* srow = stab + l * NHD;
#pragma unroll
          for (int j = 0; j < 2; ++j) {
            int dlo = j * 16 + lr, dhi = dlo + 32;
            float xlo = acc[i][j][rg] + bias[fbase + dlo];
            float xhi = acc[i][j + 2][rg] + bias[fbase + dhi];
            float olo = xlo * crow[dlo] - xhi * srow[dlo];
            float ohi = xhi * crow[dhi] + xlo * srow[dhi];
            rowp[dlo] = (bf16_t)olo;
            rowp[dhi] = (bf16_t)ohi;
          }
        }
    } else if (t == 2) {
#pragma unroll
      for (int i = 0; i < 4; ++i)
#pragma unroll
        for (int rg = 0; rg < 4; ++rg) {
          int mm = mtile * 128 + wm * 64 + i * 16 + lg * 4 + rg;
          int bb = mm >> 11, l = mm & (NL - 1);
#pragma unroll
          for (int j = 0; j < 4; ++j) {
            int d = j * 16 + lr;
            float x = acc[i][j][rg] + b2[fbase + d];
            Vt[((bb * NH + h) * NHD + d) * NL + l] = (bf16_t)x;
          }
        }
    } else {
#pragma unroll
      for (int i = 0; i < 4; ++i)
#pragma unroll
        for (int rg = 0; rg < 4; ++rg) {
          int mm = mtile * 128 + wm * 64 + i * 16 + lg * 4 + rg;
#pragma unroll
          for (int j = 0; j < 4; ++j) {
            int f = fbase + j * 16 + lr;
            Gp[mm * ND + f] = acc[i][j][rg] + b3[f];
          }
        }
    }
  }
}

// ---------------------------------------------------------------- flash attention
// swapped-QK^T 32x32 structure: 4 waves x 32 q-rows, KVBLK=64, double-buffered LDS.
// grid (L/128, B*H) with XCD swizzle; block 256.
__global__ __launch_bounds__(256) void attn_kernel(
    const bf16_t* __restrict__ Qr, const bf16_t* __restrict__ Kr, const bf16_t* __restrict__ Vt,
    const int* __restrict__ mask, const float* __restrict__ Gp, bf16_t* __restrict__ X) {
  __shared__ bf16_t lK[2][64 * 64];
  __shared__ bf16_t lV[2][64 * 64];

  // XCD-aware swizzle: 512 blocks, 8 XCDs -> 64 consecutive swz per XCD (bh-chunks)
  int lin = blockIdx.y * gridDim.x + blockIdx.x;
  int swz = (lin & 7) * 64 + (lin >> 3);
  const int qb = swz & 15, bh = swz >> 4;
  const int bb = bh >> 4, h = bh & 15;

  const int tid = threadIdx.x, lane = tid & 63, w = tid >> 6;
  const int ql = lane & 31, hi = lane >> 5;
  const float SL = 0.125f * 1.44269504f;  // 1/sqrt(64) * log2(e)

  const bf16_t* Kbh = Kr + bh * NL * NHD;
  const bf16_t* Vbh = Vt + bh * NHD * NL;
  const int q = qb * 128 + w * 32 + ql;

  // Q fragments (B-operand layout): lane holds Q[q][16c + 8hi + i]
  const bf16_t* Qp = Qr + (bh * NL + q) * NHD + 8 * hi;
  bf16x8 qf[4];
#pragma unroll
  for (int c = 0; c < 4; ++c) qf[c] = *(const bf16x8*)(Qp + 16 * c);

  f32x16 acc[2];
#pragma unroll
  for (int dt = 0; dt < 2; ++dt)
#pragma unroll
    for (int r = 0; r < 16; ++r) acc[dt][r] = 0.f;
  float mrun = -1e30f, lrun = 0.f;

  // prologue: stage tile 0
#pragma unroll
  for (int p2 = 0; p2 < 2; ++p2) {
    int u = p2 * 256 + tid;
    int r = u >> 3, c = u & 7, cs = c ^ (r & 7);
    async_load16(Kbh + r * NHD + cs * 8, &lK[0][u * 8]);
    async_load16(Vbh + r * NL + cs * 8, &lV[0][u * 8]);
  }
  int curmv = mask[bb * NL + lane];
  __syncthreads();

  int buf = 0;
  for (int t = 0; t < NL / 64; ++t) {
    int nextmv = 0;
    if (t + 1 < NL / 64) {
      int kb1 = (t + 1) * 64;
#pragma unroll
      for (int p2 = 0; p2 < 2; ++p2) {
        int u = p2 * 256 + tid;
        int r = u >> 3, c = u & 7, cs = c ^ (r & 7);
        async_load16(Kbh + (kb1 + r) * NHD + cs * 8, &lK[buf ^ 1][u * 8]);
        async_load16(Vbh + r * NL + kb1 + cs * 8, &lV[buf ^ 1][u * 8]);
      }
      nextmv = mask[bb * NL + kb1 + lane];
    }

    unsigned long long bm = __ballot(curmv != 0);
    unsigned bmw0 = (unsigned)bm, bmw1 = (unsigned)(bm >> 32);
    const bf16_t* lKb = lK[buf];
    const bf16_t* lVb = lV[buf];

    // ---- S^T = K Q^T : two 32x32 tiles (k in [32t2, 32t2+32))
    f32x16 st[2];
    __builtin_amdgcn_s_setprio(1);
#pragma unroll
    for (int t2 = 0; t2 < 2; ++t2) {
      int row = 32 * t2 + ql;
      const bf16_t* kbase = lKb + row * 64;
      f32x16 s;
#pragma unroll
      for (int r = 0; r < 16; ++r) s[r] = 0.f;
#pragma unroll
      for (int c = 0; c < 4; ++c) {
        int un = (2 * c + hi) ^ (row & 7);
        bf16x8 kf = *(const bf16x8*)(kbase + un * 8);
        s = __builtin_amdgcn_mfma_f32_32x32x16_bf16(kf, qf[c], s, 0, 0, 0);
      }
      st[t2] = s;
    }
    __builtin_amdgcn_s_setprio(0);

    // ---- per-lane online softmax (lane owns column q; 32 of 64 k's local)
    float mx = -__builtin_inff();
#pragma unroll
    for (int t2 = 0; t2 < 2; ++t2) {
      unsigned bmw = t2 ? bmw1 : bmw0;
#pragma unroll
      for (int r = 0; r < 16; ++r) {
        int kl = 8 * (r >> 2) + 4 * hi + (r & 3);  // bit index in this 32-k word
        float s = ((bmw >> kl) & 1u) ? -__builtin_inff() : st[t2][r] * SL;
        st[t2][r] = s;
        mx = fmaxf(mx, s);
      }
    }
    mx = fmaxf(mx, __shfl_xor(mx, 32, 64));
    float mnew = fmaxf(mrun, mx);
    float cf = exp2f(mrun - mnew);
    float rsum = 0.f;
#pragma unroll
    for (int t2 = 0; t2 < 2; ++t2)
#pragma unroll
      for (int r = 0; r < 16; ++r) {
        float p = exp2f(st[t2][r] - mnew);
        st[t2][r] = p;
        rsum += p;
      }
    rsum += __shfl_xor(rsum, 32, 64);
    lrun = lrun * cf + rsum;
    mrun = mnew;
#pragma unroll
    for (int dt = 0; dt < 2; ++dt)
#pragma unroll
      for (int r = 0; r < 16; ++r) acc[dt][r] *= cf;

    // ---- P -> bf16 B-operand fragments via cvt_pk + permlane32_swap
    unsigned wds[2][4][2];
#pragma unroll
    for (int t2 = 0; t2 < 2; ++t2)
#pragma unroll
      for (int r1 = 0; r1 < 4; ++r1) {
        wds[t2][r1][0] = cvtpk_bf16(st[t2][4 * r1 + 0], st[t2][4 * r1 + 1]);
        wds[t2][r1][1] = cvtpk_bf16(st[t2][4 * r1 + 2], st[t2][4 * r1 + 3]);
      }
    bf16x8 pf[4];
#pragma unroll
    for (int kc = 0; kc < 4; ++kc) {
      int t2 = kc >> 1, r1a = 2 * (kc & 1);
      unsigned a0 = wds[t2][r1a][0], b0 = wds[t2][r1a + 1][0];
      unsigned a1 = wds[t2][r1a][1], b1 = wds[t2][r1a + 1][1];
      pl32_swap(a0, b0);
      pl32_swap(a1, b1);
      union { unsigned u[4]; bf16x8 v; } uu;
      uu.u[0] = a0; uu.u[1] = a1; uu.u[2] = b0; uu.u[3] = b1;
      pf[kc] = uu.v;
    }

    // ---- acc^T[d][q] += V^T P^T
    __builtin_amdgcn_s_setprio(1);
#pragma unroll
    for (int dt = 0; dt < 2; ++dt) {
      int row = 32 * dt + ql;
      const bf16_t* vbase = lVb + row * 64;
      f32x16 a = acc[dt];
#pragma unroll
      for (int kc = 0; kc < 4; ++kc) {
        int un = (2 * kc + hi) ^ (row & 7);
        bf16x8 vf = *(const bf16x8*)(vbase + un * 8);
        a = __builtin_amdgcn_mfma_f32_32x32x16_bf16(vf, pf[kc], a, 0, 0, 0);
      }
      acc[dt] = a;
    }
    __builtin_amdgcn_s_setprio(0);

    __syncthreads();
    curmv = nextmv;
    buf ^= 1;
  }

  // ---- epilogue: /l, * sigmoid(gate), -> bf16 X (B,L,D)
  float rinv = lrun > 0.f ? 1.f / lrun : 0.f;
  const int rowbase = (bb * NL + q) * ND + h * NHD;
#pragma unroll
  for (int dt = 0; dt < 2; ++dt)
#pragma unroll
    for (int r1 = 0; r1 < 4; ++r1) {
      int dbase = 32 * dt + 8 * r1 + 4 * hi;
      float4 g4 = *(const float4*)(Gp + rowbase + dbase);
      float gg[4] = {g4.x, g4.y, g4.z, g4.w};
      bf16x4 o;
#pragma unroll
      for (int j = 0; j < 4; ++j) {
        float gate = 1.f / (1.f + exp2f(-1.44269504f * gg[j]));
        o[j] = (bf16_t)(acc[dt][4 * r1 + j] * rinv * gate);
      }
      *(bf16x4*)(X + rowbase + dbase) = o;
    }
}

// ---------------------------------------------------------------- launch
extern "C" void kernel_launch(void* const* d_in, const int* in_sizes, int n_in,
                              void* d_out, int out_size, void* d_ws, size_t ws_size,
                              hipStream_t stream) {
  const float* query = (const float*)d_in[0];
  const float* key   = (const float*)d_in[1];
  const float* value = (const float*)d_in[2];
  const int*   maskp = (const int*)d_in[3];
  const float* rcos  = (const float*)d_in[4];
  const float* rsin  = (const float*)d_in[5];
  const float* Wq = (const float*)d_in[6];  const float* bq = (const float*)d_in[7];
  const float* Wk = (const float*)d_in[8];  const float* bk = (const float*)d_in[9];
  const float* Wv = (const float*)d_in[10]; const float* bv = (const float*)d_in[11];
  const float* Wg = (const float*)d_in[12]; const float* bg = (const float*)d_in[13];
  const float* Wo = (const float*)d_in[14]; const float* bo = (const float*)d_in[15];

  constexpr size_t MB = 1ull << 20;
  char* ws = (char*)d_ws;
  bf16_t* qbb = (bf16_t*)(ws + 0 * MB);
  bf16_t* kbb = (bf16_t*)(ws + 8 * MB);
  bf16_t* vbb = (bf16_t*)(ws + 16 * MB);
  bf16_t* wqb = (bf16_t*)(ws + 24 * MB);
  bf16_t* wkb = (bf16_t*)(ws + 26 * MB);
  bf16_t* wvb = (bf16_t*)(ws + 28 * MB);
  bf16_t* wgb = (bf16_t*)(ws + 30 * MB);
  bf16_t* wob = (bf16_t*)(ws + 32 * MB);
  bf16_t* Qr  = (bf16_t*)(ws + 34 * MB);
  bf16_t* Kr  = (bf16_t*)(ws + 42 * MB);
  bf16_t* Vt  = (bf16_t*)(ws + 50 * MB);
  float*  Gp  = (float*)(ws + 58 * MB);
  bf16_t* Xb  = (bf16_t*)(ws + 74 * MB);

  cvt_kernel<<<4096, 256, 0, stream>>>(query, qbb, (NM * ND) / 4);
  cvt_kernel<<<4096, 256, 0, stream>>>(key,   kbb, (NM * ND) / 4);
  cvt_kernel<<<4096, 256, 0, stream>>>(value, vbb, (NM * ND) / 4);
  cvt_kernel<<<1024, 256, 0, stream>>>(Wq, wqb, (ND * ND) / 4);
  cvt_kernel<<<1024, 256, 0, stream>>>(Wk, wkb, (ND * ND) / 4);
  cvt_kernel<<<1024, 256, 0, stream>>>(Wv, wvb, (ND * ND) / 4);
  cvt_kernel<<<1024, 256, 0, stream>>>(Wg, wgb, (ND * ND) / 4);
  cvt_kernel<<<1024, 256, 0, stream>>>(Wo, wob, (ND * ND) / 4);

  gemm_kernel<1><<<dim3(32, 32), 256, 0, stream>>>(
      qbb, kbb, vbb, wqb, wkb, wvb, wgb, bq, bk, bv, bg, rcos, rsin,
      Qr, Kr, Vt, Gp, nullptr);

  attn_kernel<<<dim3(16, 32), 256, 0, stream>>>(Qr, Kr, Vt, maskp, Gp, Xb);

  gemm_kernel<0><<<dim3(8, 32), 256, 0, stream>>>(
      Xb, nullptr, nullptr, wob, nullptr, nullptr, nullptr,
      bo, nullptr, nullptr, nullptr, nullptr, nullptr,
      nullptr, nullptr, nullptr, nullptr, (float*)d_out);
}